// Round 17
// baseline (215.809 us; speedup 1.0000x reference)
//
#include <hip/hip_runtime.h>
#include <hip/hip_bf16.h>

#define N_ROWS 8192
#define DIM 512
#define SCALE 2.659f
#define MAXLOGIT 2.659f
#define LOG2E 1.4426950408889634f
#define NCHUNK 16
#define CHUNK 512
#define BM 128
#define BN 128
#define NCLS 128
#define GEMM_BLKS 1024   // 64 rowblks x 16 chunks

typedef __attribute__((ext_vector_type(8))) short short8;
typedef __attribute__((ext_vector_type(4))) float f32x4;

// zero region: rs(8192) + cs(8192) + c_txt(65536) + c_img(65536) + cnt(128)
#define ZERO_F4 36896

__device__ __forceinline__ unsigned short f2bf(float f) {
    unsigned int u = __float_as_uint(f);
    u += 0x7fffu + ((u >> 16) & 1u);
    return (unsigned short)(u >> 16);
}

// ---------------------------------------------------------------- normalize
// One wave handles image row i AND text row i; also zeroes accumulators and
// out[0]; emits self-dot <a_i,b_i> for label==-1 rows.
__global__ __launch_bounds__(256) void norm_cast_kernel(
    const float* __restrict__ text, const float* __restrict__ image,
    const int* __restrict__ labels,
    unsigned short* __restrict__ imgn, unsigned short* __restrict__ txtn,
    float4* __restrict__ zbase, float* __restrict__ sd, float* __restrict__ out)
{
    int zi = blockIdx.x * 256 + threadIdx.x;
    if (zi < ZERO_F4) zbase[zi] = make_float4(0.f, 0.f, 0.f, 0.f);
    if (zi == 0) out[0] = 0.f;

    int row  = blockIdx.x * 4 + (threadIdx.x >> 6);
    int lane = threadIdx.x & 63;
    const float4* si = (const float4*)(image + (size_t)row * DIM) + lane * 2;
    const float4* st = (const float4*)(text  + (size_t)row * DIM) + lane * 2;
    float4 a = si[0], b = si[1], c = st[0], d = st[1];
    float ssa = a.x*a.x + a.y*a.y + a.z*a.z + a.w*a.w
              + b.x*b.x + b.y*b.y + b.z*b.z + b.w*b.w;
    float sst = c.x*c.x + c.y*c.y + c.z*c.z + c.w*c.w
              + d.x*d.x + d.y*d.y + d.z*d.z + d.w*d.w;
    float sab = a.x*c.x + a.y*c.y + a.z*c.z + a.w*c.w
              + b.x*d.x + b.y*d.y + b.z*d.z + b.w*d.w;
    #pragma unroll
    for (int m = 1; m < 64; m <<= 1) {
        ssa += __shfl_xor(ssa, m, 64);
        sst += __shfl_xor(sst, m, 64);
        sab += __shfl_xor(sab, m, 64);
    }
    float sca = 1.0f / fmaxf(sqrtf(ssa), 1e-12f);
    float sct = 1.0f / fmaxf(sqrtf(sst), 1e-12f);
    uint4 oi, ot;
    oi.x = (unsigned)f2bf(a.x*sca) | ((unsigned)f2bf(a.y*sca) << 16);
    oi.y = (unsigned)f2bf(a.z*sca) | ((unsigned)f2bf(a.w*sca) << 16);
    oi.z = (unsigned)f2bf(b.x*sca) | ((unsigned)f2bf(b.y*sca) << 16);
    oi.w = (unsigned)f2bf(b.z*sca) | ((unsigned)f2bf(b.w*sca) << 16);
    ot.x = (unsigned)f2bf(c.x*sct) | ((unsigned)f2bf(c.y*sct) << 16);
    ot.y = (unsigned)f2bf(c.z*sct) | ((unsigned)f2bf(c.w*sct) << 16);
    ot.z = (unsigned)f2bf(d.x*sct) | ((unsigned)f2bf(d.y*sct) << 16);
    ot.w = (unsigned)f2bf(d.z*sct) | ((unsigned)f2bf(d.w*sct) << 16);
    *((uint4*)(imgn + (size_t)row * DIM) + lane) = oi;
    *((uint4*)(txtn + (size_t)row * DIM) + lane) = ot;
    if (lane == 0)
        sd[row] = (labels[row] < 0) ? sab * sca * sct : 0.0f;
}

// ---------------------------------------------------------------- fused GEMM
// Blocks [0, GEMM_BLKS): 128x128 tiles, BARRIER-FREE K-loop. Each wave owns
//   PRIVATE 64x32 A/B panels (2 buffers): no cross-wave LDS sharing, so no
//   per-step rendezvous. Per step: ds_read own panels -> 16 MFMA -> issue
//   stage(g+2) into the buffer this wave's reads just retired -> counted
//   vmcnt(8) (stage(g+1) landed; stage(g+2) stays in flight).
//   FIX vs r16: one ASYNC16 covers 64 lanes x 16B = 512 SHORTS, so the four
//   16-row group destinations are {0,512,1024,1536} (r16's {0,1024,2048,
//   3072} overflowed into the next wave's panel -> corruption).
// Blocks [GEMM_BLKS, +2048): class-sum path (8 slices x 128 cls x 2 mats).
// Swizzle (round-9 verified, conflicts=0; same 64B row stride): pre-swizzled
//   global src k-chunk (l&3)^((l>>3)&3), linear LDS dest; read slot
//   q^((lm>>1)&3).
#define ASYNC16(gp, lp) \
  __builtin_amdgcn_global_load_lds((const __attribute__((address_space(1))) void*)(gp), \
                                   (__attribute__((address_space(3))) void*)(lp), 16, 0, 0)

#define SFENCE __builtin_amdgcn_sched_barrier(0)

// per-wave private stage: 64 rows of A (rows rowBase+wr*64..+63) and 64 rows
// of B (rows tcol+wc*64..+63), 32-col K-slice each; 8 loads per lane.
#define STAGE_W(b, tcol, k0)                                                  \
  {                                                                           \
    const unsigned short* Ap = A + (size_t)(rowBase + wr*64 + srow) * DIM     \
                                 + (k0) + spsw;                               \
    const unsigned short* Bp = B + (size_t)((tcol) + wc*64 + srow) * DIM      \
                                 + (k0) + spsw;                               \
    ASYNC16(Ap,            &Ald[b][w][0]);                                    \
    ASYNC16(Ap + 16 * DIM, &Ald[b][w][512]);                                  \
    ASYNC16(Ap + 32 * DIM, &Ald[b][w][1024]);                                 \
    ASYNC16(Ap + 48 * DIM, &Ald[b][w][1536]);                                 \
    ASYNC16(Bp,            &Bld[b][w][0]);                                    \
    ASYNC16(Bp + 16 * DIM, &Bld[b][w][512]);                                  \
    ASYNC16(Bp + 32 * DIM, &Bld[b][w][1024]);                                 \
    ASYNC16(Bp + 48 * DIM, &Bld[b][w][1536]);                                 \
  }

__global__ __launch_bounds__(256, 2) void gemm_fused_kernel(
    const unsigned short* __restrict__ imgn, const unsigned short* __restrict__ txtn,
    const int* __restrict__ labels,
    float* __restrict__ rs, float* __restrict__ cs,
    float* __restrict__ c_txt, float* __restrict__ c_img, int* __restrict__ cnt)
{
    __shared__ unsigned short Ald[2][4][64 * 32];   // [buf][wave][4KB] = 32 KB
    __shared__ unsigned short Bld[2][4][64 * 32];   // 32 KB
    __shared__ float red[2][BM];                    // 1 KB
    __shared__ float colb[2][CHUNK];                // 4 KB
    __shared__ int   list[1024];                    // 4 KB (class path)
    __shared__ int   lcount;

    int tid  = threadIdx.x;

    // ---------------- class-sum path ----------------
    if (blockIdx.x >= GEMM_BLKS) {
        int blk = blockIdx.x - GEMM_BLKS;
        int cls = blk & (NCLS - 1);
        int mat = (blk >> 7) & 1;              // 0: txt sums, 1: img sums
        int slc = blk >> 8;                    // 0..7
        const unsigned* src = (const unsigned*)(mat ? imgn : txtn);
        float* dst = mat ? c_img : c_txt;
        if (tid == 0) lcount = 0;
        __syncthreads();
        int base0 = slc * 1024;
        #pragma unroll
        for (int it = 0; it < 4; ++it) {
            int i  = base0 + it * 256 + tid;
            int lb = labels[i];
            if (lb == cls) { int s = atomicAdd(&lcount, 1); list[s & 1023] = i; }
        }
        __syncthreads();
        int m = lcount;
        if (m == 0) return;
        if (mat == 0 && tid == 0) atomicAdd(&cnt[cls], m);
        float a0 = 0.f, a1 = 0.f;
        int r = 0;
        for (; r + 4 <= m; r += 4) {           // 4 independent loads in flight
            unsigned u0 = src[(size_t)list[r]   * (DIM/2) + tid];
            unsigned u1 = src[(size_t)list[r+1] * (DIM/2) + tid];
            unsigned u2 = src[(size_t)list[r+2] * (DIM/2) + tid];
            unsigned u3 = src[(size_t)list[r+3] * (DIM/2) + tid];
            a0 += __uint_as_float((u0 & 0xffffu) << 16) + __uint_as_float((u1 & 0xffffu) << 16)
                + __uint_as_float((u2 & 0xffffu) << 16) + __uint_as_float((u3 & 0xffffu) << 16);
            a1 += __uint_as_float(u0 & 0xffff0000u) + __uint_as_float(u1 & 0xffff0000u)
                + __uint_as_float(u2 & 0xffff0000u) + __uint_as_float(u3 & 0xffff0000u);
        }
        for (; r < m; ++r) {
            unsigned u = src[(size_t)list[r] * (DIM/2) + tid];
            a0 += __uint_as_float((u & 0xffffu) << 16);
            a1 += __uint_as_float(u & 0xffff0000u);
        }
        unsafeAtomicAdd(&dst[(size_t)cls * DIM + tid*2],     a0);
        unsafeAtomicAdd(&dst[(size_t)cls * DIM + tid*2 + 1], a1);
        return;
    }

    // ---------------- GEMM path ----------------
    int bid    = blockIdx.x;
    int rowblk = bid & 63;
    int chunk  = bid >> 6;        // consecutive bids share a chunk -> B L2-hot
    const unsigned short* A = imgn;
    const unsigned short* B = txtn;
    int rowBase  = rowblk * BM;
    int colBase0 = chunk * CHUNK;

    int lane = tid & 63;
    int w    = tid >> 6;
    int wr   = w >> 1, wc = w & 1;
    int q    = lane >> 4;
    int lm   = lane & 15;
    int qa   = q ^ ((lm >> 1) & 3);   // swizzled read slot

    float s_acc[16];
    #pragma unroll
    for (int i = 0; i < 16; ++i) s_acc[i] = 0.f;

    int srow = lane >> 2;                               // staging row in group
    int spsw = (((lane & 3) ^ ((lane >> 3) & 3)) * 8);  // swizzled src k-chunk

    const float C1 = SCALE * LOG2E;
    const float C2 = -MAXLOGIT * LOG2E;

    // prologue: per-wave stage step 0 -> buf0, step 1 -> buf1 (16 loads);
    // vmcnt(8) => oldest 8 (stage 0) landed, stage 1 still in flight.
    STAGE_W(0, colBase0, 0);
    STAGE_W(1, colBase0, 32);
    SFENCE;
    asm volatile("s_waitcnt vmcnt(8)" ::: "memory");
    SFENCE;

    #pragma unroll 1
    for (int tile = 0; tile < CHUNK / BN; ++tile) {
        f32x4 acc[4][4];
        #pragma unroll
        for (int mi = 0; mi < 4; ++mi)
          #pragma unroll
          for (int ni = 0; ni < 4; ++ni)
            acc[mi][ni] = (f32x4){0.f, 0.f, 0.f, 0.f};

        #pragma unroll
        for (int kt = 0; kt < DIM / 32; ++kt) {
            // step g = tile*16 + kt; buffer = g&1 = kt&1 (static after unroll)
            const int bcur = kt & 1;

            // reads of this wave's private panels (stage(g) landed at the
            // end of step g-1 via vmcnt(8); no other wave writes them).
            short8 af[4], bf[4];
            #pragma unroll
            for (int mi = 0; mi < 4; ++mi)
                af[mi] = *(const short8*)(&Ald[bcur][w][(mi*16 + lm)*32 + qa*8]);
            #pragma unroll
            for (int ni = 0; ni < 4; ++ni)
                bf[ni] = *(const short8*)(&Bld[bcur][w][(ni*16 + lm)*32 + qa*8]);
            #pragma unroll
            for (int mi = 0; mi < 4; ++mi)
              #pragma unroll
              for (int ni = 0; ni < 4; ++ni)
                acc[mi][ni] = __builtin_amdgcn_mfma_f32_16x16x32_bf16(
                                  af[mi], bf[ni], acc[mi][ni], 0, 0, 0);

            // stage(g+2) into bcur: this wave's reads of bcur retired (the
            // MFMAs above lgkm-waited on them); SFENCE pins the order.
            SFENCE;
            int g2 = tile * 16 + kt + 2;
            if (g2 < 64) {
                STAGE_W(bcur, colBase0 + (g2 >> 4) * BN, (g2 & 15) * 32);
            }

            // tile epilogue before the wait: extra latency cover.
            if (kt == DIM / 32 - 1) {
                #pragma unroll
                for (int ni = 0; ni < 4; ++ni) {
                    float csum = 0.f;
                    #pragma unroll
                    for (int mi = 0; mi < 4; ++mi) {
                      #pragma unroll
                      for (int r = 0; r < 4; ++r) {
                        float e = __builtin_amdgcn_exp2f(fmaf(acc[mi][ni][r], C1, C2));
                        s_acc[mi*4 + r] += e;
                        csum += e;
                      }
                    }
                    csum += __shfl_xor(csum, 16, 64);
                    csum += __shfl_xor(csum, 32, 64);
                    if (q == 0)
                        colb[wr][tile*BN + wc*64 + ni*16 + lm] = csum;
                }
            }

            // counted per-wave wait: the 8 newest outstanding loads are
            // stage(g+2); <=8 outstanding => stage(g+1) landed. No barrier —
            // waves are fully independent. Tail (no stage issued) drains.
            SFENCE;
            if (g2 < 64) asm volatile("s_waitcnt vmcnt(8)" ::: "memory");
            else         asm volatile("s_waitcnt vmcnt(0)" ::: "memory");
            SFENCE;
        }
    }

    // row stats: reduce across the 16 column-lanes (low 4 lane bits)
    #pragma unroll
    for (int idx = 0; idx < 16; ++idx) {
        float s = s_acc[idx];
        #pragma unroll
        for (int m = 1; m < 16; m <<= 1) s += __shfl_xor(s, m, 64);
        s_acc[idx] = s;
    }
    if (lm == 0) {
        #pragma unroll
        for (int idx = 0; idx < 16; ++idx) {
            int rl = wr*64 + (idx>>2)*16 + q*4 + (idx&3);
            red[wc][rl] = s_acc[idx];
        }
    }
    __syncthreads();   // single rendezvous: cross-wave reduction buffers ready
    if (tid < BM)
        unsafeAtomicAdd(&rs[rowBase + tid], red[0][tid] + red[1][tid]);
    for (int c = tid; c < CHUNK; c += 256)
        unsafeAtomicAdd(&cs[colBase0 + c], colb[0][c] + colb[1][c]);
}

// ---------------------------------------------------------------- final loss
// loss*2N = Sum_i (M + log rs_i) + Sum_i (M + log cs_i)
//           - 2*scale*[ Sum_l <c_img[l],c_txt[l]>/cnt_l + Sum_{lab=-1} <a_i,b_i> ]
__global__ __launch_bounds__(256) void loss_tail_kernel(
    const float* __restrict__ rs, const float* __restrict__ cs,
    const float* __restrict__ sd, const float* __restrict__ c_txt,
    const float* __restrict__ c_img, const int* __restrict__ cnt,
    float* __restrict__ out)
{
    __shared__ float wsum[4];
    int tid = threadIdx.x, lane = tid & 63, w = tid >> 6;
    int gidx = blockIdx.x * 256 + tid;           // 0..16383
    float local;
    if (gidx < N_ROWS)
        local = (MAXLOGIT + logf(rs[gidx])) - 2.0f * SCALE * sd[gidx];
    else
        local = MAXLOGIT + logf(cs[gidx - N_ROWS]);

    // class-dot portion: 2 classes per block, 4 dims per thread
    int cls = blockIdx.x * 2 + (tid >> 7);       // 0..127
    int e0  = (tid & 127) * 4;
    int n   = cnt[cls];
    if (n > 0) {
        float4 x = *(const float4*)(c_txt + (size_t)cls * DIM + e0);
        float4 y = *(const float4*)(c_img + (size_t)cls * DIM + e0);
        float dotp = x.x*y.x + x.y*y.y + x.z*y.z + x.w*y.w;
        local -= 2.0f * SCALE * dotp / (float)n;
    }

    #pragma unroll
    for (int m = 1; m < 64; m <<= 1) local += __shfl_xor(local, m, 64);
    if (lane == 0) wsum[w] = local;
    __syncthreads();
    if (tid == 0)
        unsafeAtomicAdd(out, (wsum[0] + wsum[1] + wsum[2] + wsum[3])
                             * (1.0f / (2 * N_ROWS)));
}

// ---------------------------------------------------------------- launch
extern "C" void kernel_launch(void* const* d_in, const int* in_sizes, int n_in,
                              void* d_out, int out_size, void* d_ws, size_t ws_size,
                              hipStream_t stream)
{
    const float* text   = (const float*)d_in[0];
    const float* image  = (const float*)d_in[1];
    const int*   labels = (const int*)d_in[2];

    unsigned short* imgn = (unsigned short*)d_ws;
    unsigned short* txtn = imgn + (size_t)N_ROWS * DIM;
    char* p = (char*)d_ws + 2 * (size_t)N_ROWS * DIM * sizeof(unsigned short);
    float* rs    = (float*)p;                       // 8192 f32  (zeroed)
    float* cs    = rs + N_ROWS;                     // 8192 f32  (zeroed)
    float* c_txt = cs + N_ROWS;                     // 128*512 f32 (zeroed)
    float* c_img = c_txt + (size_t)NCLS * DIM;      // 128*512 f32 (zeroed)
    int*   cnt   = (int*)(c_img + (size_t)NCLS * DIM); // 128 (zeroed)
    float* sd    = (float*)(cnt + NCLS);            // 8192 f32 (fully written)
    float* out = (float*)d_out;

    hipLaunchKernelGGL(norm_cast_kernel, dim3(N_ROWS / 4), dim3(256), 0, stream,
                       text, image, labels, imgn, txtn, (float4*)rs, sd, out);
    hipLaunchKernelGGL(gemm_fused_kernel, dim3(GEMM_BLKS + 2048), dim3(256), 0, stream,
                       imgn, txtn, labels, rs, cs, c_txt, c_img, cnt);
    hipLaunchKernelGGL(loss_tail_kernel, dim3(64), dim3(256), 0, stream,
                       rs, cs, sd, c_txt, c_img, cnt, out);
}